// Round 13
// baseline (176.319 us; speedup 1.0000x reference)
//
#include <hip/hip_runtime.h>

#define NN 10000     // nodes
#define HF 128       // hidden feats
#define INF_ 256     // in feats
#define CLS 64       // classes
#define NR 8         // bucket segments (one per XCD)
#define SEG 32       // slots per segment (64B line); per-seg deg ~Poisson(8)
#define CAPT (NR * SEG)   // 256 slots/node
#define NP 10240     // cnt8 per-replica stride (ints)
#define RT  (NN / 16)  // 625 row tiles (gemm1)
#define NPB 8          // nodes per aggfin block
#define NB  (NN / NPB) // 1250 aggfin blocks
#define LDP (HF + 8)   // padded LDS row stride (shorts)

typedef __attribute__((ext_vector_type(8))) short short8;   // 8 bf16 (4 VGPRs)
typedef __attribute__((ext_vector_type(4))) float f32x4;

__device__ __forceinline__ unsigned short f2bf(float f) {
    unsigned u = __builtin_bit_cast(unsigned, f);
    u = (u + 0x7fffu + ((u >> 16) & 1u)) >> 16;   // RNE
    return (unsigned short)u;
}
__device__ __forceinline__ float bfbits2f(unsigned u) {  // u = bf16 in low 16
    u <<= 16;
    return __builtin_bit_cast(float, u);
}

// ---------------- MFMA helpers ----------------
// Verified gfx950 fragment layouts (learn_hip m89/m120):
//   A frag: lane holds A[m=lane&15][k=(lane>>4)*8 + 0..7]  (16B contiguous)
//   B frag: lane holds W[n=lane&15][k=(lane>>4)*8 + 0..7]  (W row-major [N][K] = B^T)
//   C/D:    col=lane&15, row=(lane>>4)*4 + reg
// row0 = base row of the 16-row A fragment; lda in elements.

template <int K, int NC>
__device__ __forceinline__
void mfma_rows16(int row0, int col0,
                 const unsigned short* __restrict__ A, int lda,
                 const unsigned short* __restrict__ W, f32x4* acc) {
    int lane = threadIdx.x & 63;
    int m = lane & 15, quad = lane >> 4;
    const unsigned short* arow = A + (size_t)(row0 + m) * lda + quad * 8;
    const short8* bp[NC];
#pragma unroll
    for (int c = 0; c < NC; ++c)
        bp[c] = (const short8*)(W + (size_t)(col0 + c * 16 + m) * K + quad * 8);
#pragma unroll
    for (int k0 = 0; k0 < K; k0 += 32) {
        short8 a = *(const short8*)(arow + k0);
#pragma unroll
        for (int c = 0; c < NC; ++c)
            acc[c] = __builtin_amdgcn_mfma_f32_16x16x32_bf16(a, bp[c][k0 >> 3], acc[c], 0, 0, 0);
    }
}

__device__ __forceinline__ short8 pack8(float4 a, float4 b) {
    short8 r;
    r[0] = (short)f2bf(a.x); r[1] = (short)f2bf(a.y);
    r[2] = (short)f2bf(a.z); r[3] = (short)f2bf(a.w);
    r[4] = (short)f2bf(b.x); r[5] = (short)f2bf(b.y);
    r[6] = (short)f2bf(b.z); r[7] = (short)f2bf(b.w);
    return r;
}

// input projection: h0 = relu(x @ W_lin.T + b_lin); x, W_lin f32 (cvt in-loop —
// hides under the latency-bound fill anyway)
__device__ __forceinline__
void gemm1_wave(int row_tile, int col0, const float* __restrict__ x,
                const float* __restrict__ Wlin, const float* __restrict__ blin,
                unsigned short* __restrict__ h0) {
    int lane = threadIdx.x & 63;
    int m = lane & 15, quad = lane >> 4;
    const float* ar = x    + (size_t)(row_tile * 16 + m) * INF_ + quad * 8;
    const float* w0 = Wlin + (size_t)(col0 +  0 + m) * INF_ + quad * 8;
    const float* w1 = Wlin + (size_t)(col0 + 16 + m) * INF_ + quad * 8;
    const float* w2 = Wlin + (size_t)(col0 + 32 + m) * INF_ + quad * 8;
    const float* w3 = Wlin + (size_t)(col0 + 48 + m) * INF_ + quad * 8;
    f32x4 acc[4] = {};
#pragma unroll
    for (int k0 = 0; k0 < INF_; k0 += 32) {
        short8 a  = pack8(*(const float4*)(ar + k0), *(const float4*)(ar + k0 + 4));
        short8 b0 = pack8(*(const float4*)(w0 + k0), *(const float4*)(w0 + k0 + 4));
        short8 b1 = pack8(*(const float4*)(w1 + k0), *(const float4*)(w1 + k0 + 4));
        short8 b2 = pack8(*(const float4*)(w2 + k0), *(const float4*)(w2 + k0 + 4));
        short8 b3 = pack8(*(const float4*)(w3 + k0), *(const float4*)(w3 + k0 + 4));
        acc[0] = __builtin_amdgcn_mfma_f32_16x16x32_bf16(a, b0, acc[0], 0, 0, 0);
        acc[1] = __builtin_amdgcn_mfma_f32_16x16x32_bf16(a, b1, acc[1], 0, 0, 0);
        acc[2] = __builtin_amdgcn_mfma_f32_16x16x32_bf16(a, b2, acc[2], 0, 0, 0);
        acc[3] = __builtin_amdgcn_mfma_f32_16x16x32_bf16(a, b3, acc[3], 0, 0, 0);
    }
#pragma unroll
    for (int c = 0; c < 4; ++c) {
        int colg = col0 + c * 16 + m;
        float bv = blin[colg];
#pragma unroll
        for (int r = 0; r < 4; ++r) {
            int rowg = row_tile * 16 + quad * 4 + r;
            h0[(size_t)rowg * HF + colg] = f2bf(fmaxf(acc[c][r] + bv, 0.f));
        }
    }
}

// ---------------- fused: gemm1 || segmented bucket fill || weight cvt ----------------
#define GB 313
#define FB 2500   // 1 edge/thread (R6 lesson: waves > per-thread ILP)
#define CB 288

__global__ __launch_bounds__(256)
void fused_k(const float* __restrict__ x, const float* __restrict__ Wlin,
             const float* __restrict__ blin, unsigned short* __restrict__ h0,
             const int* __restrict__ src, const int* __restrict__ dst,
             int* __restrict__ cnt8, unsigned short* __restrict__ colb, int E,
             const float* __restrict__ Wl1, const float* __restrict__ Wr1,
             const float* __restrict__ Wl2, const float* __restrict__ Wr2,
             const float* __restrict__ Wcls, unsigned short* __restrict__ wb) {
    int b = blockIdx.x;
    if (b < GB) {
        int wave = threadIdx.x >> 6;
        int row_tile = b * 2 + (wave >> 1);
        if (row_tile >= RT) return;
        gemm1_wave(row_tile, (wave & 1) * 64, x, Wlin, blin, h0);
    } else if (b < GB + FB) {
        // XCD-segmented scatter (R10): replica r = blockIdx%8 tracks round-robin
        // block->XCD dispatch -> each 64B colb line written by ONE XCD.
        int r = b & 7;
        int i = (b - GB) * 256 + threadIdx.x;
        if (i < E) {
            int d = dst[i];
            int pos = atomicAdd(&cnt8[r * NP + d], 1);
            if (pos < SEG) colb[(size_t)d * CAPT + r * SEG + pos] = (unsigned short)src[i];
        }
    } else {
        int i = (b - GB - FB) * 256 + threadIdx.x;
        const float* s; int off;
        if      (i < 16384) { s = Wl1;  off = 0; }
        else if (i < 32768) { s = Wr1;  off = 16384; }
        else if (i < 49152) { s = Wl2;  off = 32768; }
        else if (i < 65536) { s = Wr2;  off = 49152; }
        else if (i < 73728) { s = Wcls; off = 65536; }
        else return;
        wb[i] = f2bf(s[i - off]);
    }
}

// ---------------- per-wave mean gather: compact segments -> flat LDS list ----
// (R11 structure, bf16 rows.) Phase A: compact the 8 segments into
// cols[0..cdeg) in LDS (all-lane shfls — R2 rule). Phase B: ONE flat loop,
// 4 quad-edges/step; edge index straight from LDS (no shfl in hot loop);
// unroll 4 -> >=4 independent 256B row-gathers in flight.
__device__ __forceinline__
void gather_mean(const unsigned short* __restrict__ h,
                 const int* __restrict__ cnt8, int node,
                 const unsigned short* __restrict__ seg,   // colb + node*CAPT
                 unsigned short* __restrict__ cols,        // per-wave LDS, CAPT slots
                 unsigned short* __restrict__ msrow) {
    int lane = threadIdx.x & 63;
    int q   = lane >> 4;
    int r16 = lane & 15;

    int craw0 = 0;
    if (lane < 8) craw0 = cnt8[lane * NP + node];
    int c0 = craw0 > SEG ? SEG : craw0;
    int off0 = 0, deg = 0, cdeg = 0;
#pragma unroll
    for (int i = 0; i < 8; ++i) {                 // all-lanes-active shfls
        int ci = __shfl(c0, i);
        int ri = __shfl(craw0, i);
        if (lane > i) off0 += ci;
        cdeg += ci;
        deg  += ri;
    }
#pragma unroll
    for (int p = 0; p < 4; ++p) {
        int r = 2 * p + (lane >> 5);
        int j = lane & 31;
        unsigned short v = seg[r * SEG + j];
        int cr  = __shfl(c0, r);
        int orr = __shfl(off0, r);
        if (j < cr) cols[orr + j] = v;
    }

    const uint4* __restrict__ hp = (const uint4*)h;   // bf16 row = 16 uint4
    float a0 = 0.f, a1 = 0.f, a2 = 0.f, a3 = 0.f;
    float a4 = 0.f, a5 = 0.f, a6 = 0.f, a7 = 0.f;
#pragma unroll 4
    for (int e0 = 0; e0 < cdeg; e0 += 4) {
        int e = e0 + q;
        if (e < cdeg) {                            // no shfl inside: safe guard
            int s = (int)cols[e];
            uint4 v = hp[(size_t)s * 16 + r16];
            a0 += bfbits2f(v.x & 0xffffu); a1 += bfbits2f(v.x >> 16);
            a2 += bfbits2f(v.y & 0xffffu); a3 += bfbits2f(v.y >> 16);
            a4 += bfbits2f(v.z & 0xffffu); a5 += bfbits2f(v.z >> 16);
            a6 += bfbits2f(v.w & 0xffffu); a7 += bfbits2f(v.w >> 16);
        }
    }
    a0 += __shfl_xor(a0, 16); a0 += __shfl_xor(a0, 32);
    a1 += __shfl_xor(a1, 16); a1 += __shfl_xor(a1, 32);
    a2 += __shfl_xor(a2, 16); a2 += __shfl_xor(a2, 32);
    a3 += __shfl_xor(a3, 16); a3 += __shfl_xor(a3, 32);
    a4 += __shfl_xor(a4, 16); a4 += __shfl_xor(a4, 32);
    a5 += __shfl_xor(a5, 16); a5 += __shfl_xor(a5, 32);
    a6 += __shfl_xor(a6, 16); a6 += __shfl_xor(a6, 32);
    a7 += __shfl_xor(a7, 16); a7 += __shfl_xor(a7, 32);
    if (q == 0) {
        float inv = (deg > 0) ? 1.0f / (float)deg : 0.f;
        uint4 o;
        o.x = (unsigned)f2bf(a0 * inv) | ((unsigned)f2bf(a1 * inv) << 16);
        o.y = (unsigned)f2bf(a2 * inv) | ((unsigned)f2bf(a3 * inv) << 16);
        o.z = (unsigned)f2bf(a4 * inv) | ((unsigned)f2bf(a5 * inv) << 16);
        o.w = (unsigned)f2bf(a6 * inv) | ((unsigned)f2bf(a7 * inv) << 16);
        ((uint4*)msrow)[r16] = o;
    }
}

// ---------------- aggfin1: 8 nodes/block, 512 threads (tail-balance fix) -----
// 8 waves gather 8 nodes -> ms rows 0-7. Self-GEMM h0@Wr1 uses 16-row MFMA
// fragments with only rows 0-7 stored (D row r depends only on A row r, so
// garbage rows 8-15 — uninit LDS / next block's rows — only pollute discarded
// D rows). Grid 1250 -> 4.88 blocks/CU at 4/CU cap (vs R11's 2.44 at 2/CU:
// ~19% tail -> ~2.4%).
__global__ __launch_bounds__(512)
void aggfin1_k(const unsigned short* __restrict__ h0, const int* __restrict__ cnt8,
               const unsigned short* __restrict__ colb,
               const unsigned short* __restrict__ Wr, const unsigned short* __restrict__ Wl,
               const float* __restrict__ bias, unsigned short* __restrict__ h1) {
    __shared__ __align__(16) unsigned short ms[16][LDP];   // rows 8-15 garbage (ok)
    __shared__ __align__(16) unsigned short colsLds[NPB][CAPT];
    int wave = threadIdx.x >> 6;
    int lane = threadIdx.x & 63;
    int m = lane & 15, quad = lane >> 4;
    int row0 = blockIdx.x * NPB;
    int node = row0 + wave;
    gather_mean(h0, cnt8, node, colb + (size_t)node * CAPT,
                &colsLds[wave][0], &ms[wave][0]);

    f32x4 acc[1] = {};
    mfma_rows16<HF, 1>(row0, wave * 16, h0, HF, Wr, acc);      // h0 @ Wr1 (8 waves x 16 cols)
    __syncthreads();
    mfma_rows16<HF, 1>(0, wave * 16, &ms[0][0], LDP, Wl, acc); // + means @ Wl1
    if (quad < 2) {                                            // rows 0-7 only
        int colg = wave * 16 + m;
        float bv = bias[colg];
#pragma unroll
        for (int r = 0; r < 4; ++r) {
            int rowg = row0 + quad * 4 + r;
            h1[(size_t)rowg * HF + colg] = f2bf(acc[0][r] + bv);
        }
    }
}

// ---------------- aggfin2cls: 8 nodes/block + relu + classifier --------------
__global__ __launch_bounds__(512)
void aggfin2cls_k(const unsigned short* __restrict__ h1, const int* __restrict__ cnt8,
                  const unsigned short* __restrict__ colb,
                  const unsigned short* __restrict__ Wr, const unsigned short* __restrict__ Wl,
                  const float* __restrict__ bias, const unsigned short* __restrict__ Wc,
                  float* __restrict__ out) {
    __shared__ __align__(16) unsigned short ms[16][LDP];
    __shared__ __align__(16) unsigned short h2s[16][LDP];   // rows 8-15 garbage (ok)
    __shared__ __align__(16) unsigned short colsLds[NPB][CAPT];
    int wave = threadIdx.x >> 6;
    int lane = threadIdx.x & 63;
    int m = lane & 15, quad = lane >> 4;
    int row0 = blockIdx.x * NPB;
    int node = row0 + wave;
    gather_mean(h1, cnt8, node, colb + (size_t)node * CAPT,
                &colsLds[wave][0], &ms[wave][0]);

    f32x4 acc[1] = {};
    mfma_rows16<HF, 1>(row0, wave * 16, h1, HF, Wr, acc);      // h1 @ Wr2
    __syncthreads();
    mfma_rows16<HF, 1>(0, wave * 16, &ms[0][0], LDP, Wl, acc); // + means @ Wl2
    {
        int colg = wave * 16 + m;
        float bv = bias[colg];
#pragma unroll
        for (int r = 0; r < 4; ++r) {
            // write all 16 rows (8-15 garbage; fmaxf(NaN,0)=0) — discarded later
            h2s[quad * 4 + r][colg] = f2bf(fmaxf(acc[0][r] + bv, 0.f));
        }
    }
    __syncthreads();
    if (wave < 4) {
        f32x4 cacc[1] = {};
        mfma_rows16<HF, 1>(0, wave * 16, &h2s[0][0], LDP, Wc, cacc); // h2 @ W_cls
        if (quad < 2) {                                              // rows 0-7 only
            int colg = wave * 16 + m;
#pragma unroll
            for (int r = 0; r < 4; ++r) {
                int rowg = row0 + quad * 4 + r;
                out[(size_t)rowg * CLS + colg] = cacc[0][r];
            }
        }
    }
}

// ---------------- launch ----------------

extern "C" void kernel_launch(void* const* d_in, const int* in_sizes, int n_in,
                              void* d_out, int out_size, void* d_ws, size_t ws_size,
                              hipStream_t stream) {
    const float* x      = (const float*)d_in[0];
    const int*   ei     = (const int*)d_in[1];
    const float* W_lin  = (const float*)d_in[2];
    const float* b_lin  = (const float*)d_in[3];
    const float* Wl1    = (const float*)d_in[4];
    const float* bl1    = (const float*)d_in[5];
    const float* Wr1    = (const float*)d_in[6];
    const float* Wl2    = (const float*)d_in[7];
    const float* bl2    = (const float*)d_in[8];
    const float* Wr2    = (const float*)d_in[9];
    const float* W_cls  = (const float*)d_in[10];
    float* out = (float*)d_out;

    const int E = in_sizes[1] / 2;
    const int* src = ei;
    const int* dst = ei + E;

    // workspace layout (bf16 stored as ushort); h0/h1 over-allocated +16 rows
    // so 16-row A-fragments of the last aggfin block stay in bounds.
    unsigned short* wb  = (unsigned short*)d_ws;          // 73728 weights bf16
    unsigned short* wbl1 = wb;
    unsigned short* wbr1 = wb + 16384;
    unsigned short* wbl2 = wb + 32768;
    unsigned short* wbr2 = wb + 49152;
    unsigned short* wbc  = wb + 65536;
    unsigned short* h0  = wb + 73728;                     // (NN+16)*HF
    unsigned short* h1  = h0 + (size_t)(NN + 16) * HF;    // (NN+16)*HF
    int* cnt8 = (int*)(h1 + (size_t)(NN + 16) * HF);      // NR*NP
    unsigned short* colb = (unsigned short*)(cnt8 + NR * NP);  // NN*CAPT

    hipMemsetAsync(cnt8, 0, NR * NP * sizeof(int), stream);

    // ---- fused: input projection + relu || segmented fill || weight cvt ----
    fused_k<<<GB + FB + CB, 256, 0, stream>>>(
        x, W_lin, b_lin, h0, src, dst, cnt8, colb, E,
        Wl1, Wr1, Wl2, Wr2, W_cls, wb);

    // ---- sage1 (agg + GEMM fused, 8 nodes/block) ----
    aggfin1_k<<<NB, 512, 0, stream>>>(h0, cnt8, colb, wbr1, wbl1, bl1, h1);

    // ---- sage2 + relu + classifier (8 nodes/block) ----
    aggfin2cls_k<<<NB, 512, 0, stream>>>(h1, cnt8, colb, wbr2, wbl2, bl2, wbc, out);
}

// Round 14
// 163.970 us; speedup vs baseline: 1.0753x; 1.0753x over previous
//
#include <hip/hip_runtime.h>

#define NN 10000     // nodes
#define HF 128       // hidden feats
#define INF_ 256     // in feats
#define CLS 64       // classes
#define NR 8         // bucket segments (one per XCD)
#define SEG 32       // slots per segment (64B line); per-seg deg ~Poisson(8)
#define CAPT (NR * SEG)   // 256 slots/node
#define NP 10240     // cnt8 per-replica stride (ints)
#define RT  (NN / 16)  // 625 row tiles
#define LDP (HF + 8)   // padded LDS row stride (shorts)

typedef __attribute__((ext_vector_type(8))) short short8;   // 8 bf16 (4 VGPRs)
typedef __attribute__((ext_vector_type(4))) float f32x4;

__device__ __forceinline__ unsigned short f2bf(float f) {
    unsigned u = __builtin_bit_cast(unsigned, f);
    u = (u + 0x7fffu + ((u >> 16) & 1u)) >> 16;   // RNE
    return (unsigned short)u;
}
__device__ __forceinline__ float bfbits2f(unsigned u) {  // u = bf16 in low 16
    u <<= 16;
    return __builtin_bit_cast(float, u);
}

// ---------------- MFMA helpers ----------------
// Verified gfx950 fragment layouts (learn_hip m89/m120):
//   A frag: lane holds A[m=lane&15][k=(lane>>4)*8 + 0..7]  (16B contiguous)
//   B frag: lane holds W[n=lane&15][k=(lane>>4)*8 + 0..7]  (W row-major [N][K] = B^T)
//   C/D:    col=lane&15, row=(lane>>4)*4 + reg

template <int K, int NC>
__device__ __forceinline__
void mfma_cols(int row_tile, int col0,
               const unsigned short* __restrict__ A, int lda,
               const unsigned short* __restrict__ W, f32x4* acc) {
    int lane = threadIdx.x & 63;
    int m = lane & 15, quad = lane >> 4;
    const unsigned short* arow = A + (size_t)(row_tile * 16 + m) * lda + quad * 8;
    const short8* bp[NC];
#pragma unroll
    for (int c = 0; c < NC; ++c)
        bp[c] = (const short8*)(W + (size_t)(col0 + c * 16 + m) * K + quad * 8);
#pragma unroll
    for (int k0 = 0; k0 < K; k0 += 32) {
        short8 a = *(const short8*)(arow + k0);
#pragma unroll
        for (int c = 0; c < NC; ++c)
            acc[c] = __builtin_amdgcn_mfma_f32_16x16x32_bf16(a, bp[c][k0 >> 3], acc[c], 0, 0, 0);
    }
}

__device__ __forceinline__ short8 pack8(float4 a, float4 b) {
    short8 r;
    r[0] = (short)f2bf(a.x); r[1] = (short)f2bf(a.y);
    r[2] = (short)f2bf(a.z); r[3] = (short)f2bf(a.w);
    r[4] = (short)f2bf(b.x); r[5] = (short)f2bf(b.y);
    r[6] = (short)f2bf(b.z); r[7] = (short)f2bf(b.w);
    return r;
}

// input projection: h0 = relu(x @ W_lin.T + b_lin); x, W_lin f32 (cvt in-loop —
// hides under the latency-bound fill anyway)
__device__ __forceinline__
void gemm1_wave(int row_tile, int col0, const float* __restrict__ x,
                const float* __restrict__ Wlin, const float* __restrict__ blin,
                unsigned short* __restrict__ h0) {
    int lane = threadIdx.x & 63;
    int m = lane & 15, quad = lane >> 4;
    const float* ar = x    + (size_t)(row_tile * 16 + m) * INF_ + quad * 8;
    const float* w0 = Wlin + (size_t)(col0 +  0 + m) * INF_ + quad * 8;
    const float* w1 = Wlin + (size_t)(col0 + 16 + m) * INF_ + quad * 8;
    const float* w2 = Wlin + (size_t)(col0 + 32 + m) * INF_ + quad * 8;
    const float* w3 = Wlin + (size_t)(col0 + 48 + m) * INF_ + quad * 8;
    f32x4 acc[4] = {};
#pragma unroll
    for (int k0 = 0; k0 < INF_; k0 += 32) {
        short8 a  = pack8(*(const float4*)(ar + k0), *(const float4*)(ar + k0 + 4));
        short8 b0 = pack8(*(const float4*)(w0 + k0), *(const float4*)(w0 + k0 + 4));
        short8 b1 = pack8(*(const float4*)(w1 + k0), *(const float4*)(w1 + k0 + 4));
        short8 b2 = pack8(*(const float4*)(w2 + k0), *(const float4*)(w2 + k0 + 4));
        short8 b3 = pack8(*(const float4*)(w3 + k0), *(const float4*)(w3 + k0 + 4));
        acc[0] = __builtin_amdgcn_mfma_f32_16x16x32_bf16(a, b0, acc[0], 0, 0, 0);
        acc[1] = __builtin_amdgcn_mfma_f32_16x16x32_bf16(a, b1, acc[1], 0, 0, 0);
        acc[2] = __builtin_amdgcn_mfma_f32_16x16x32_bf16(a, b2, acc[2], 0, 0, 0);
        acc[3] = __builtin_amdgcn_mfma_f32_16x16x32_bf16(a, b3, acc[3], 0, 0, 0);
    }
#pragma unroll
    for (int c = 0; c < 4; ++c) {
        int colg = col0 + c * 16 + m;
        float bv = blin[colg];
#pragma unroll
        for (int r = 0; r < 4; ++r) {
            int rowg = row_tile * 16 + quad * 4 + r;
            h0[(size_t)rowg * HF + colg] = f2bf(fmaxf(acc[c][r] + bv, 0.f));
        }
    }
}

// ---------------- fused: gemm1 || segmented bucket fill || weight cvt ----------------
#define GB 313
#define FB 2500   // 1 edge/thread (R6 lesson: waves > per-thread ILP)
#define CB 288

__global__ __launch_bounds__(256)
void fused_k(const float* __restrict__ x, const float* __restrict__ Wlin,
             const float* __restrict__ blin, unsigned short* __restrict__ h0,
             const int* __restrict__ src, const int* __restrict__ dst,
             int* __restrict__ cnt8, unsigned short* __restrict__ colb, int E,
             const float* __restrict__ Wl1, const float* __restrict__ Wr1,
             const float* __restrict__ Wl2, const float* __restrict__ Wr2,
             const float* __restrict__ Wcls, unsigned short* __restrict__ wb) {
    int b = blockIdx.x;
    if (b < GB) {
        int wave = threadIdx.x >> 6;
        int row_tile = b * 2 + (wave >> 1);
        if (row_tile >= RT) return;
        gemm1_wave(row_tile, (wave & 1) * 64, x, Wlin, blin, h0);
    } else if (b < GB + FB) {
        // XCD-segmented scatter (R10): replica r = blockIdx%8 tracks round-robin
        // block->XCD dispatch -> each 64B colb line written by ONE XCD.
        int r = b & 7;
        int i = (b - GB) * 256 + threadIdx.x;
        if (i < E) {
            int d = dst[i];
            int pos = atomicAdd(&cnt8[r * NP + d], 1);
            if (pos < SEG) colb[(size_t)d * CAPT + r * SEG + pos] = (unsigned short)src[i];
        }
    } else {
        int i = (b - GB - FB) * 256 + threadIdx.x;
        const float* s; int off;
        if      (i < 16384) { s = Wl1;  off = 0; }
        else if (i < 32768) { s = Wr1;  off = 16384; }
        else if (i < 49152) { s = Wl2;  off = 32768; }
        else if (i < 65536) { s = Wr2;  off = 49152; }
        else if (i < 73728) { s = Wcls; off = 65536; }
        else return;
        wb[i] = f2bf(s[i - off]);
    }
}

// ---------------- compaction: one node's 8 segments -> flat LDS list ----------
// all-lane shfls (R2 rule); returns cdeg via ref, deg via ref.
__device__ __forceinline__
void compact_node(const int* __restrict__ cnt8, int node,
                  const unsigned short* __restrict__ seg,
                  unsigned short* __restrict__ cols, int& cdeg, int& deg) {
    int lane = threadIdx.x & 63;
    int craw0 = 0;
    if (lane < 8) craw0 = cnt8[lane * NP + node];
    int c0 = craw0 > SEG ? SEG : craw0;
    int off0 = 0; cdeg = 0; deg = 0;
#pragma unroll
    for (int i = 0; i < 8; ++i) {                 // all-lanes-active shfls
        int ci = __shfl(c0, i);
        int ri = __shfl(craw0, i);
        if (lane > i) off0 += ci;
        cdeg += ci;
        deg  += ri;
    }
#pragma unroll
    for (int p = 0; p < 4; ++p) {
        int r = 2 * p + (lane >> 5);
        int j = lane & 31;
        unsigned short v = seg[r * SEG + j];
        int cr  = __shfl(c0, r);
        int orr = __shfl(off0, r);
        if (j < cr) cols[orr + j] = v;
    }
}

// ---------------- dual-node mean gather: 2 interleaved streams per wave -------
// Two compacted lists gathered in ONE flat loop -> up to 8 independent 256B
// row-loads in flight per wave (4 lane-groups x 2 streams). No shfl in the hot
// loop (guards safe). Writes both ms rows.
__device__ __forceinline__
void gather2(const unsigned short* __restrict__ h,
             const int* __restrict__ cnt8, int nodeA, int nodeB,
             const unsigned short* __restrict__ colb,
             unsigned short* __restrict__ colsA, unsigned short* __restrict__ colsB,
             unsigned short* __restrict__ msA, unsigned short* __restrict__ msB) {
    int lane = threadIdx.x & 63;
    int q   = lane >> 4;
    int r16 = lane & 15;
    int cdA, dgA, cdB, dgB;
    compact_node(cnt8, nodeA, colb + (size_t)nodeA * CAPT, colsA, cdA, dgA);
    compact_node(cnt8, nodeB, colb + (size_t)nodeB * CAPT, colsB, cdB, dgB);

    const uint4* __restrict__ hp = (const uint4*)h;   // bf16 row = 16 uint4
    float a0 = 0.f, a1 = 0.f, a2 = 0.f, a3 = 0.f;
    float a4 = 0.f, a5 = 0.f, a6 = 0.f, a7 = 0.f;
    float b0 = 0.f, b1 = 0.f, b2 = 0.f, b3 = 0.f;
    float b4 = 0.f, b5 = 0.f, b6 = 0.f, b7 = 0.f;
    int cdmax = cdA > cdB ? cdA : cdB;                // wave-uniform
#pragma unroll 4
    for (int e0 = 0; e0 < cdmax; e0 += 4) {
        int e = e0 + q;
        if (e < cdA) {
            int s = (int)colsA[e];
            uint4 v = hp[(size_t)s * 16 + r16];
            a0 += bfbits2f(v.x & 0xffffu); a1 += bfbits2f(v.x >> 16);
            a2 += bfbits2f(v.y & 0xffffu); a3 += bfbits2f(v.y >> 16);
            a4 += bfbits2f(v.z & 0xffffu); a5 += bfbits2f(v.z >> 16);
            a6 += bfbits2f(v.w & 0xffffu); a7 += bfbits2f(v.w >> 16);
        }
        if (e < cdB) {
            int s = (int)colsB[e];
            uint4 v = hp[(size_t)s * 16 + r16];
            b0 += bfbits2f(v.x & 0xffffu); b1 += bfbits2f(v.x >> 16);
            b2 += bfbits2f(v.y & 0xffffu); b3 += bfbits2f(v.y >> 16);
            b4 += bfbits2f(v.z & 0xffffu); b5 += bfbits2f(v.z >> 16);
            b6 += bfbits2f(v.w & 0xffffu); b7 += bfbits2f(v.w >> 16);
        }
    }
    // reduce across the 4 lane-groups (bits 4,5) — all lanes active
    a0 += __shfl_xor(a0, 16); a0 += __shfl_xor(a0, 32);
    a1 += __shfl_xor(a1, 16); a1 += __shfl_xor(a1, 32);
    a2 += __shfl_xor(a2, 16); a2 += __shfl_xor(a2, 32);
    a3 += __shfl_xor(a3, 16); a3 += __shfl_xor(a3, 32);
    a4 += __shfl_xor(a4, 16); a4 += __shfl_xor(a4, 32);
    a5 += __shfl_xor(a5, 16); a5 += __shfl_xor(a5, 32);
    a6 += __shfl_xor(a6, 16); a6 += __shfl_xor(a6, 32);
    a7 += __shfl_xor(a7, 16); a7 += __shfl_xor(a7, 32);
    b0 += __shfl_xor(b0, 16); b0 += __shfl_xor(b0, 32);
    b1 += __shfl_xor(b1, 16); b1 += __shfl_xor(b1, 32);
    b2 += __shfl_xor(b2, 16); b2 += __shfl_xor(b2, 32);
    b3 += __shfl_xor(b3, 16); b3 += __shfl_xor(b3, 32);
    b4 += __shfl_xor(b4, 16); b4 += __shfl_xor(b4, 32);
    b5 += __shfl_xor(b5, 16); b5 += __shfl_xor(b5, 32);
    b6 += __shfl_xor(b6, 16); b6 += __shfl_xor(b6, 32);
    b7 += __shfl_xor(b7, 16); b7 += __shfl_xor(b7, 32);
    if (q == 0) {
        float ia = (dgA > 0) ? 1.0f / (float)dgA : 0.f;
        float ib = (dgB > 0) ? 1.0f / (float)dgB : 0.f;
        uint4 oa, ob;
        oa.x = (unsigned)f2bf(a0 * ia) | ((unsigned)f2bf(a1 * ia) << 16);
        oa.y = (unsigned)f2bf(a2 * ia) | ((unsigned)f2bf(a3 * ia) << 16);
        oa.z = (unsigned)f2bf(a4 * ia) | ((unsigned)f2bf(a5 * ia) << 16);
        oa.w = (unsigned)f2bf(a6 * ia) | ((unsigned)f2bf(a7 * ia) << 16);
        ob.x = (unsigned)f2bf(b0 * ib) | ((unsigned)f2bf(b1 * ib) << 16);
        ob.y = (unsigned)f2bf(b2 * ib) | ((unsigned)f2bf(b3 * ib) << 16);
        ob.z = (unsigned)f2bf(b4 * ib) | ((unsigned)f2bf(b5 * ib) << 16);
        ob.w = (unsigned)f2bf(b6 * ib) | ((unsigned)f2bf(b7 * ib) << 16);
        ((uint4*)msA)[r16] = oa;
        ((uint4*)msB)[r16] = ob;
    }
}

// ---------------- aggfin1: 16 nodes/block, 512 threads, 2 nodes/wave ----------
// Block b <-> row-tile b (R13 lesson: keep block=16-row-tile alignment).
// 8 waves each gather TWO nodes (interleaved streams) -> ms rows 2w, 2w+1.
// Self-GEMM h0@Wr1: 8 waves x 16 cols over the 16-row tile (exactly R11's
// shape, no redundant A reads). After barrier: + means@Wl1 (LDS A) + bias.
__global__ __launch_bounds__(512)
void aggfin1_k(const unsigned short* __restrict__ h0, const int* __restrict__ cnt8,
               const unsigned short* __restrict__ colb,
               const unsigned short* __restrict__ Wr, const unsigned short* __restrict__ Wl,
               const float* __restrict__ bias, unsigned short* __restrict__ h1) {
    __shared__ __align__(16) unsigned short ms[16][LDP];
    __shared__ __align__(16) unsigned short colsLds[16][CAPT];
    int wave = threadIdx.x >> 6;
    int nodeA = blockIdx.x * 16 + wave * 2;
    gather2(h0, cnt8, nodeA, nodeA + 1, colb,
            &colsLds[wave * 2][0], &colsLds[wave * 2 + 1][0],
            &ms[wave * 2][0], &ms[wave * 2 + 1][0]);

    f32x4 acc[1] = {};
    mfma_cols<HF, 1>(blockIdx.x, wave * 16, h0, HF, Wr, acc);  // h0 @ Wr1
    __syncthreads();
    mfma_cols<HF, 1>(0, wave * 16, &ms[0][0], LDP, Wl, acc);   // + means @ Wl1
    {
        int lane = threadIdx.x & 63;
        int m = lane & 15, quad = lane >> 4;
        int colg = wave * 16 + m;
        float bv = bias[colg];
#pragma unroll
        for (int r = 0; r < 4; ++r) {
            int rowg = blockIdx.x * 16 + quad * 4 + r;
            h1[(size_t)rowg * HF + colg] = f2bf(acc[0][r] + bv);
        }
    }
}

// ---------------- aggfin2cls: same + relu + classifier ------------------------
__global__ __launch_bounds__(512)
void aggfin2cls_k(const unsigned short* __restrict__ h1, const int* __restrict__ cnt8,
                  const unsigned short* __restrict__ colb,
                  const unsigned short* __restrict__ Wr, const unsigned short* __restrict__ Wl,
                  const float* __restrict__ bias, const unsigned short* __restrict__ Wc,
                  float* __restrict__ out) {
    __shared__ __align__(16) unsigned short ms[16][LDP];
    __shared__ __align__(16) unsigned short h2s[16][LDP];
    __shared__ __align__(16) unsigned short colsLds[16][CAPT];
    int wave = threadIdx.x >> 6;
    int lane = threadIdx.x & 63;
    int m = lane & 15, quad = lane >> 4;
    int nodeA = blockIdx.x * 16 + wave * 2;
    gather2(h1, cnt8, nodeA, nodeA + 1, colb,
            &colsLds[wave * 2][0], &colsLds[wave * 2 + 1][0],
            &ms[wave * 2][0], &ms[wave * 2 + 1][0]);

    f32x4 acc[1] = {};
    mfma_cols<HF, 1>(blockIdx.x, wave * 16, h1, HF, Wr, acc);  // h1 @ Wr2
    __syncthreads();
    mfma_cols<HF, 1>(0, wave * 16, &ms[0][0], LDP, Wl, acc);   // + means @ Wl2
    {
        int colg = wave * 16 + m;
        float bv = bias[colg];
#pragma unroll
        for (int r = 0; r < 4; ++r) {
            float v = acc[0][r] + bv;
            h2s[quad * 4 + r][colg] = f2bf(fmaxf(v, 0.f));     // relu -> LDS
        }
    }
    __syncthreads();
    if (wave < 4) {
        f32x4 cacc[1] = {};
        mfma_cols<HF, 1>(0, wave * 16, &h2s[0][0], LDP, Wc, cacc); // h2 @ W_cls
        int colg = wave * 16 + m;
#pragma unroll
        for (int r = 0; r < 4; ++r) {
            int rowg = blockIdx.x * 16 + quad * 4 + r;
            out[(size_t)rowg * CLS + colg] = cacc[0][r];
        }
    }
}

// ---------------- launch ----------------

extern "C" void kernel_launch(void* const* d_in, const int* in_sizes, int n_in,
                              void* d_out, int out_size, void* d_ws, size_t ws_size,
                              hipStream_t stream) {
    const float* x      = (const float*)d_in[0];
    const int*   ei     = (const int*)d_in[1];
    const float* W_lin  = (const float*)d_in[2];
    const float* b_lin  = (const float*)d_in[3];
    const float* Wl1    = (const float*)d_in[4];
    const float* bl1    = (const float*)d_in[5];
    const float* Wr1    = (const float*)d_in[6];
    const float* Wl2    = (const float*)d_in[7];
    const float* bl2    = (const float*)d_in[8];
    const float* Wr2    = (const float*)d_in[9];
    const float* W_cls  = (const float*)d_in[10];
    float* out = (float*)d_out;

    const int E = in_sizes[1] / 2;
    const int* src = ei;
    const int* dst = ei + E;

    // workspace layout (bf16 stored as ushort)
    unsigned short* wb  = (unsigned short*)d_ws;          // 73728 weights bf16
    unsigned short* wbl1 = wb;
    unsigned short* wbr1 = wb + 16384;
    unsigned short* wbl2 = wb + 32768;
    unsigned short* wbr2 = wb + 49152;
    unsigned short* wbc  = wb + 65536;
    unsigned short* h0  = wb + 73728;                     // NN*HF
    unsigned short* h1  = h0 + (size_t)NN * HF;           // NN*HF
    int* cnt8 = (int*)(h1 + (size_t)NN * HF);             // NR*NP
    unsigned short* colb = (unsigned short*)(cnt8 + NR * NP);  // NN*CAPT

    hipMemsetAsync(cnt8, 0, NR * NP * sizeof(int), stream);

    // ---- fused: input projection + relu || segmented fill || weight cvt ----
    fused_k<<<GB + FB + CB, 256, 0, stream>>>(
        x, W_lin, b_lin, h0, src, dst, cnt8, colb, E,
        Wl1, Wr1, Wl2, Wr2, W_cls, wb);

    // ---- sage1 (agg + GEMM fused, 2 nodes/wave) ----
    aggfin1_k<<<RT, 512, 0, stream>>>(h0, cnt8, colb, wbr1, wbl1, bl1, h1);

    // ---- sage2 + relu + classifier ----
    aggfin2cls_k<<<RT, 512, 0, stream>>>(h1, cnt8, colb, wbr2, wbl2, bl2, wbc, out);
}